// Round 4
// baseline (585.817 us; speedup 1.0000x reference)
//
#include <hip/hip_runtime.h>

#define P_SEG 50000

// ---------------------------------------------------------------------------
// Kernel 1: per-hit masked MSE accumulation into per-particle bins.
//   valid = (reconstructable > 0) && (particle_id > 0)
//   sums[pid]   += sum_d (pred[i,d] - track_params[i,d])^2
//   counts[pid] += 1
// Bins (2 * 50K fp32 = 400 KB) live in d_ws and stay L2-resident.
// ---------------------------------------------------------------------------
__global__ __launch_bounds__(256) void
objloss_accum(const float* __restrict__ pred,
              const float* __restrict__ tp,
              const int* __restrict__ pid,
              const int* __restrict__ recon,
              float* __restrict__ sums,
              float* __restrict__ counts,
              int n) {
    int stride = gridDim.x * blockDim.x;
    for (int i = blockIdx.x * blockDim.x + threadIdx.x; i < n; i += stride) {
        int p = pid[i];
        int r = recon[i];
        if ((r > 0) & (p > 0) & (p < P_SEG)) {
            // 24 bytes per row, 8B-aligned -> 3x float2 loads each.
            const float2* p2 = reinterpret_cast<const float2*>(pred) + (size_t)i * 3;
            const float2* t2 = reinterpret_cast<const float2*>(tp)   + (size_t)i * 3;
            float2 a0 = p2[0], a1 = p2[1], a2 = p2[2];
            float2 b0 = t2[0], b1 = t2[1], b2 = t2[2];
            float d0 = a0.x - b0.x;
            float d1 = a0.y - b0.y;
            float d2 = a1.x - b1.x;
            float d3 = a1.y - b1.y;
            float d4 = a2.x - b2.x;
            float d5 = a2.y - b2.y;
            float mse = d0 * d0 + d1 * d1 + d2 * d2 + d3 * d3 + d4 * d4 + d5 * d5;
            atomicAdd(&sums[p], mse);
            atomicAdd(&counts[p], 1.0f);
        }
    }
}

// ---------------------------------------------------------------------------
// Kernel 2: reduce bins -> scalar.  out = 100 * sum(present ? s/c : 0) / K.
// Single block of 1024 threads; 400 KB read (L2-hot from kernel 1).
// ---------------------------------------------------------------------------
__global__ __launch_bounds__(1024) void
objloss_finalize(const float* __restrict__ sums,
                 const float* __restrict__ counts,
                 float* __restrict__ out) {
    __shared__ float s_sum[16];
    __shared__ float s_k[16];

    float local_sum = 0.0f;
    float local_k = 0.0f;
    for (int i = threadIdx.x; i < P_SEG; i += blockDim.x) {
        float c = counts[i];
        if (c > 0.0f) {
            local_sum += sums[i] / c;
            local_k += 1.0f;
        }
    }
    // wave-64 butterfly reduce
    #pragma unroll
    for (int off = 32; off > 0; off >>= 1) {
        local_sum += __shfl_down(local_sum, off);
        local_k   += __shfl_down(local_k, off);
    }
    int wave = threadIdx.x >> 6;
    int lane = threadIdx.x & 63;
    if (lane == 0) {
        s_sum[wave] = local_sum;
        s_k[wave] = local_k;
    }
    __syncthreads();
    if (threadIdx.x == 0) {
        float tot = 0.0f, k = 0.0f;
        #pragma unroll
        for (int w = 0; w < 16; ++w) {
            tot += s_sum[w];
            k += s_k[w];
        }
        out[0] = (k > 0.0f) ? (100.0f * tot / k) : 0.0f;
    }
}

extern "C" void kernel_launch(void* const* d_in, const int* in_sizes, int n_in,
                              void* d_out, int out_size, void* d_ws, size_t ws_size,
                              hipStream_t stream) {
    // Input order (setup_inputs): W, beta, H, pred, Y, particle_id,
    //                             track_params, reconstructable
    const float* pred  = (const float*)d_in[3];
    const int*   pid   = (const int*)  d_in[5];
    const float* tp    = (const float*)d_in[6];
    const int*   recon = (const int*)  d_in[7];
    int n = in_sizes[0];  // N = 5,000,000

    float* sums   = (float*)d_ws;
    float* counts = sums + P_SEG;

    // Zero the bins (graph-capture-safe async memset).
    hipMemsetAsync(d_ws, 0, 2 * P_SEG * sizeof(float), stream);

    // Memory-bound: cap grid and grid-stride (G11).
    const int block = 256;
    const int grid = 2048;
    objloss_accum<<<grid, block, 0, stream>>>(pred, tp, pid, recon, sums, counts, n);
    objloss_finalize<<<1, 1024, 0, stream>>>(sums, counts, (float*)d_out);
}

// Round 5
// 434.115 us; speedup vs baseline: 1.3495x; 1.3495x over previous
//
#include <hip/hip_runtime.h>

#define P_SEG 50000
// Packing constant: bin value = count * PACK_C + sum_mse.
// max sum_mse/group ~9e3 << 2^24, max count < 256 -> val < 2^32, exact extract.
#define PACK_C 16777216.0   // 2^24

// ---------------------------------------------------------------------------
// Kernel 1: per-PAIR masked MSE accumulation, ONE f64 atomic per valid hit.
//   bins[pid] += (double)mse + 2^24   (i.e. count in high part, mse in low)
// ---------------------------------------------------------------------------
__global__ __launch_bounds__(256) void
objloss_accum(const float* __restrict__ pred,
              const float* __restrict__ tp,
              const int* __restrict__ pid,
              const int* __restrict__ recon,
              double* __restrict__ bins,
              int n) {
    int i = blockIdx.x * blockDim.x + threadIdx.x;   // pair index
    int base = i * 2;
    if (base >= n) return;

    if (base + 1 < n) {
        // Vector path: 2 hits = 12 floats = 3 x float4 (48B, 16B-aligned).
        int2 pp = *reinterpret_cast<const int2*>(pid + base);
        int2 rr = *reinterpret_cast<const int2*>(recon + base);
        const float4* pa = reinterpret_cast<const float4*>(pred + (size_t)base * 6);
        const float4* tb = reinterpret_cast<const float4*>(tp   + (size_t)base * 6);
        float4 a0 = pa[0], a1 = pa[1], a2 = pa[2];
        float4 b0 = tb[0], b1 = tb[1], b2 = tb[2];

        float e0 = a0.x - b0.x, e1 = a0.y - b0.y, e2 = a0.z - b0.z;
        float e3 = a0.w - b0.w, e4 = a1.x - b1.x, e5 = a1.y - b1.y;
        float m0 = e0*e0 + e1*e1 + e2*e2 + e3*e3 + e4*e4 + e5*e5;

        float f0 = a1.z - b1.z, f1 = a1.w - b1.w, f2 = a2.x - b2.x;
        float f3 = a2.y - b2.y, f4 = a2.z - b2.z, f5 = a2.w - b2.w;
        float m1 = f0*f0 + f1*f1 + f2*f2 + f3*f3 + f4*f4 + f5*f5;

        bool v0 = (rr.x > 0) & (pp.x > 0) & (pp.x < P_SEG);
        bool v1 = (rr.y > 0) & (pp.y > 0) & (pp.y < P_SEG);
        if (v0) atomicAdd(&bins[pp.x], (double)m0 + PACK_C);
        if (v1) atomicAdd(&bins[pp.y], (double)m1 + PACK_C);
    } else {
        // Scalar tail (odd n).
        int p = pid[base];
        int r = recon[base];
        if ((r > 0) & (p > 0) & (p < P_SEG)) {
            float m = 0.0f;
            #pragma unroll
            for (int d = 0; d < 6; ++d) {
                float e = pred[(size_t)base * 6 + d] - tp[(size_t)base * 6 + d];
                m += e * e;
            }
            atomicAdd(&bins[p], (double)m + PACK_C);
        }
    }
}

// ---------------------------------------------------------------------------
// Kernel 2: unpack bins -> scalar.  out = 100 * sum(present ? s/c : 0) / K.
// Single block of 1024 threads; 400 KB read (L2-hot from kernel 1).
// ---------------------------------------------------------------------------
__global__ __launch_bounds__(1024) void
objloss_finalize(const double* __restrict__ bins,
                 float* __restrict__ out) {
    __shared__ double s_sum[16];
    __shared__ double s_k[16];

    double local_sum = 0.0;
    double local_k = 0.0;
    for (int i = threadIdx.x; i < P_SEG; i += blockDim.x) {
        double v = bins[i];
        double cnt = floor(v * (1.0 / PACK_C));
        if (cnt > 0.0) {
            double s = v - cnt * PACK_C;
            local_sum += s / cnt;
            local_k += 1.0;
        }
    }
    #pragma unroll
    for (int off = 32; off > 0; off >>= 1) {
        local_sum += __shfl_down(local_sum, off);
        local_k   += __shfl_down(local_k, off);
    }
    int wave = threadIdx.x >> 6;
    int lane = threadIdx.x & 63;
    if (lane == 0) {
        s_sum[wave] = local_sum;
        s_k[wave] = local_k;
    }
    __syncthreads();
    if (threadIdx.x == 0) {
        double tot = 0.0, k = 0.0;
        #pragma unroll
        for (int w = 0; w < 16; ++w) {
            tot += s_sum[w];
            k += s_k[w];
        }
        out[0] = (k > 0.0) ? (float)(100.0 * tot / k) : 0.0f;
    }
}

extern "C" void kernel_launch(void* const* d_in, const int* in_sizes, int n_in,
                              void* d_out, int out_size, void* d_ws, size_t ws_size,
                              hipStream_t stream) {
    // Input order (setup_inputs): W, beta, H, pred, Y, particle_id,
    //                             track_params, reconstructable
    const float* pred  = (const float*)d_in[3];
    const int*   pid   = (const int*)  d_in[5];
    const float* tp    = (const float*)d_in[6];
    const int*   recon = (const int*)  d_in[7];
    int n = in_sizes[0];  // N = 5,000,000

    double* bins = (double*)d_ws;    // 50K * 8B = 400 KB

    hipMemsetAsync(d_ws, 0, P_SEG * sizeof(double), stream);

    const int block = 256;
    int pairs = (n + 1) / 2;
    int grid = (pairs + block - 1) / block;   // one pair per thread
    objloss_accum<<<grid, block, 0, stream>>>(pred, tp, pid, recon, bins, n);
    objloss_finalize<<<1, 1024, 0, stream>>>(bins, (float*)d_out);
}

// Round 9
// 414.605 us; speedup vs baseline: 1.4130x; 1.0471x over previous
//
#include <hip/hip_runtime.h>

#define P_SEG 50000
// Packed bin: value = count * 2^24 + sum_mse.
// sum_mse/group < ~4e3 << 2^24; count < ~500 -> value < 2^33, f64-exact unpack.
#define PACK_C 16777216.0   // 2^24
#define NBLK_FIN 256

// ---------------------------------------------------------------------------
// XCC id from hardware (gfx940+): s_getreg_b32 hwreg(HW_REG_XCC_ID=20, off 0, sz 4)
// Wave-uniform scalar read; masking &7 bounds it to our 8 copies.
// ---------------------------------------------------------------------------
__device__ __forceinline__ int xcc_id() {
    return __builtin_amdgcn_s_getreg(((4 - 1) << 11) | (0 << 6) | 20) & 7;
}

// L2-local f64 atomic add: no sc bits -> RMW executes in this XCD's L2,
// never becomes an HBM-side transaction. Only safe because each XCD has a
// private copy of the bins (indexed by xcc_id).
__device__ __forceinline__ void l2_atomic_add_f64(double* p, double v) {
    asm volatile("global_atomic_add_f64 %0, %1, off" :: "v"(p), "v"(v) : "memory");
}

// ---------------------------------------------------------------------------
// Kernel 1a: per-pair MSE accumulation into the XCD-private packed bins.
// ---------------------------------------------------------------------------
__global__ __launch_bounds__(256) void
objloss_accum_xcd(const float* __restrict__ pred,
                  const float* __restrict__ tp,
                  const int* __restrict__ pid,
                  const int* __restrict__ recon,
                  double* __restrict__ bins,   // [8][P_SEG]
                  int n) {
    int i = blockIdx.x * blockDim.x + threadIdx.x;   // pair index
    int base = i * 2;
    if (base >= n) return;

    double* mybins = bins + (size_t)xcc_id() * P_SEG;

    if (base + 1 < n) {
        int2 pp = *reinterpret_cast<const int2*>(pid + base);
        int2 rr = *reinterpret_cast<const int2*>(recon + base);
        const float4* pa = reinterpret_cast<const float4*>(pred + (size_t)base * 6);
        const float4* tb = reinterpret_cast<const float4*>(tp   + (size_t)base * 6);
        float4 a0 = pa[0], a1 = pa[1], a2 = pa[2];
        float4 b0 = tb[0], b1 = tb[1], b2 = tb[2];

        float e0 = a0.x - b0.x, e1 = a0.y - b0.y, e2 = a0.z - b0.z;
        float e3 = a0.w - b0.w, e4 = a1.x - b1.x, e5 = a1.y - b1.y;
        float m0 = e0*e0 + e1*e1 + e2*e2 + e3*e3 + e4*e4 + e5*e5;

        float f0 = a1.z - b1.z, f1 = a1.w - b1.w, f2 = a2.x - b2.x;
        float f3 = a2.y - b2.y, f4 = a2.z - b2.z, f5 = a2.w - b2.w;
        float m1 = f0*f0 + f1*f1 + f2*f2 + f3*f3 + f4*f4 + f5*f5;

        if ((rr.x > 0) & (pp.x > 0) & (pp.x < P_SEG))
            l2_atomic_add_f64(&mybins[pp.x], (double)m0 + PACK_C);
        if ((rr.y > 0) & (pp.y > 0) & (pp.y < P_SEG))
            l2_atomic_add_f64(&mybins[pp.y], (double)m1 + PACK_C);
    } else {
        int p = pid[base];
        int r = recon[base];
        if ((r > 0) & (p > 0) & (p < P_SEG)) {
            float m = 0.0f;
            #pragma unroll
            for (int d = 0; d < 6; ++d) {
                float e = pred[(size_t)base * 6 + d] - tp[(size_t)base * 6 + d];
                m += e * e;
            }
            l2_atomic_add_f64(&mybins[p], (double)m + PACK_C);
        }
    }
}

// ---------------------------------------------------------------------------
// Kernel 1b: fallback if ws_size can't hold 8 copies (single copy,
// device-scope atomics — round-5 behavior).
// ---------------------------------------------------------------------------
__global__ __launch_bounds__(256) void
objloss_accum_dev(const float* __restrict__ pred,
                  const float* __restrict__ tp,
                  const int* __restrict__ pid,
                  const int* __restrict__ recon,
                  double* __restrict__ bins,
                  int n) {
    int i = blockIdx.x * blockDim.x + threadIdx.x;
    int base = i * 2;
    if (base >= n) return;
    if (base + 1 < n) {
        int2 pp = *reinterpret_cast<const int2*>(pid + base);
        int2 rr = *reinterpret_cast<const int2*>(recon + base);
        const float4* pa = reinterpret_cast<const float4*>(pred + (size_t)base * 6);
        const float4* tb = reinterpret_cast<const float4*>(tp   + (size_t)base * 6);
        float4 a0 = pa[0], a1 = pa[1], a2 = pa[2];
        float4 b0 = tb[0], b1 = tb[1], b2 = tb[2];
        float e0 = a0.x - b0.x, e1 = a0.y - b0.y, e2 = a0.z - b0.z;
        float e3 = a0.w - b0.w, e4 = a1.x - b1.x, e5 = a1.y - b1.y;
        float m0 = e0*e0 + e1*e1 + e2*e2 + e3*e3 + e4*e4 + e5*e5;
        float f0 = a1.z - b1.z, f1 = a1.w - b1.w, f2 = a2.x - b2.x;
        float f3 = a2.y - b2.y, f4 = a2.z - b2.z, f5 = a2.w - b2.w;
        float m1 = f0*f0 + f1*f1 + f2*f2 + f3*f3 + f4*f4 + f5*f5;
        if ((rr.x > 0) & (pp.x > 0) & (pp.x < P_SEG)) atomicAdd(&bins[pp.x], (double)m0 + PACK_C);
        if ((rr.y > 0) & (pp.y > 0) & (pp.y < P_SEG)) atomicAdd(&bins[pp.y], (double)m1 + PACK_C);
    } else {
        int p = pid[base];
        int r = recon[base];
        if ((r > 0) & (p > 0) & (p < P_SEG)) {
            float m = 0.0f;
            #pragma unroll
            for (int d = 0; d < 6; ++d) {
                float e = pred[(size_t)base * 6 + d] - tp[(size_t)base * 6 + d];
                m += e * e;
            }
            atomicAdd(&bins[p], (double)m + PACK_C);
        }
    }
}

// ---------------------------------------------------------------------------
// Kernel 2: multi-block reduce over bins (sums the 8 copies), block partials.
// ---------------------------------------------------------------------------
__global__ __launch_bounds__(256) void
objloss_mid(const double* __restrict__ bins, int ncopies,
            double* __restrict__ partials) {
    double lsum = 0.0, lk = 0.0;
    int stride = gridDim.x * blockDim.x;
    for (int i = blockIdx.x * blockDim.x + threadIdx.x; i < P_SEG; i += stride) {
        double v = 0.0;
        for (int c = 0; c < ncopies; ++c) v += bins[(size_t)c * P_SEG + i];
        double cnt = floor(v * (1.0 / PACK_C));
        if (cnt > 0.0) {
            lsum += (v - cnt * PACK_C) / cnt;
            lk += 1.0;
        }
    }
    #pragma unroll
    for (int off = 32; off > 0; off >>= 1) {
        lsum += __shfl_down(lsum, off);
        lk   += __shfl_down(lk, off);
    }
    __shared__ double ss[4], sk[4];
    int w = threadIdx.x >> 6, lane = threadIdx.x & 63;
    if (lane == 0) { ss[w] = lsum; sk[w] = lk; }
    __syncthreads();
    if (threadIdx.x == 0) {
        double t = 0.0, k = 0.0;
        #pragma unroll
        for (int j = 0; j < 4; ++j) { t += ss[j]; k += sk[j]; }
        partials[2 * blockIdx.x]     = t;
        partials[2 * blockIdx.x + 1] = k;
    }
}

// ---------------------------------------------------------------------------
// Kernel 3: final scalar.
// ---------------------------------------------------------------------------
__global__ __launch_bounds__(256) void
objloss_final(const double* __restrict__ partials, float* __restrict__ out) {
    int t = threadIdx.x;
    double ls = 0.0, lk = 0.0;
    if (t < NBLK_FIN) { ls = partials[2 * t]; lk = partials[2 * t + 1]; }
    #pragma unroll
    for (int off = 32; off > 0; off >>= 1) {
        ls += __shfl_down(ls, off);
        lk += __shfl_down(lk, off);
    }
    __shared__ double ss[4], sk[4];
    int w = t >> 6, lane = t & 63;
    if (lane == 0) { ss[w] = ls; sk[w] = lk; }
    __syncthreads();
    if (t == 0) {
        double s = 0.0, k = 0.0;
        #pragma unroll
        for (int j = 0; j < 4; ++j) { s += ss[j]; k += sk[j]; }
        out[0] = (k > 0.0) ? (float)(100.0 * s / k) : 0.0f;
    }
}

extern "C" void kernel_launch(void* const* d_in, const int* in_sizes, int n_in,
                              void* d_out, int out_size, void* d_ws, size_t ws_size,
                              hipStream_t stream) {
    // Inputs: W, beta, H, pred, Y, particle_id, track_params, reconstructable
    const float* pred  = (const float*)d_in[3];
    const int*   pid   = (const int*)  d_in[5];
    const float* tp    = (const float*)d_in[6];
    const int*   recon = (const int*)  d_in[7];
    int n = in_sizes[0];  // N = 5,000,000

    size_t need8 = (size_t)8 * P_SEG * sizeof(double) + 2 * NBLK_FIN * sizeof(double);
    int ncopies = (ws_size >= need8) ? 8 : 1;

    double* bins     = (double*)d_ws;
    double* partials = bins + (size_t)ncopies * P_SEG;

    hipMemsetAsync(d_ws, 0, (size_t)ncopies * P_SEG * sizeof(double), stream);

    const int block = 256;
    int pairs = (n + 1) / 2;
    int grid = (pairs + block - 1) / block;
    if (ncopies == 8)
        objloss_accum_xcd<<<grid, block, 0, stream>>>(pred, tp, pid, recon, bins, n);
    else
        objloss_accum_dev<<<grid, block, 0, stream>>>(pred, tp, pid, recon, bins, n);

    objloss_mid<<<NBLK_FIN, block, 0, stream>>>(bins, ncopies, partials);
    objloss_final<<<1, block, 0, stream>>>(partials, (float*)d_out);
}